// Round 12
// baseline (306.114 us; speedup 1.0000x reference)
//
#include <hip/hip_runtime.h>
#include <hip/hip_bf16.h>
#include <hip/hip_fp16.h>

#define LRELU_SLOPE 0.2f
#define CSR_STRIDE 32   // bucket = 32 ints: slot 0 = count, slots 1..31 = sources

__device__ __forceinline__ float lrelu(float x) { return x > 0.f ? x : LRELU_SLOPE * x; }

typedef __attribute__((ext_vector_type(8))) short short8;
typedef __attribute__((ext_vector_type(4))) float f32x4;

__device__ __forceinline__ unsigned short f2bf(float f) {
    unsigned u = __builtin_bit_cast(unsigned, f);
    u = (u + 0x7FFFu + ((u >> 16) & 1u)) >> 16;  // RNE
    return (unsigned short)u;
}
__device__ __forceinline__ float bf2f(unsigned short b) {
    unsigned u = ((unsigned)b) << 16;
    return __builtin_bit_cast(float, u);
}

// ---------------- W pre-pack body: fp32 [K][64] -> B-fragment bf16 hi/lo ----------------
template <int K>
__device__ __forceinline__ void packW_body(const float* __restrict__ W,
                                           unsigned short* __restrict__ Bhi,
                                           unsigned short* __restrict__ Blo,
                                           int blk, int t) {
    constexpr int NKC = K / 32;
    int g = blk * 256 + t;
    if (g >= 4 * NKC * 64) return;
    int lane = g & 63;
    int kc = (g >> 6) % NKC;
    int ct = g / (64 * NKC);
    int qd = lane >> 4, col = lane & 15;
    #pragma unroll
    for (int j = 0; j < 8; j++) {
        int k = kc * 32 + qd * 8 + j;
        float w = W[(size_t)k * 64 + ct * 16 + col];
        unsigned short h = f2bf(w);
        float rem = w - bf2f(h);
        Bhi[(size_t)g * 8 + j] = h;
        Blo[(size_t)g * 8 + j] = f2bf(rem);
    }
}

// ---------------- prep — packW1 + packW2 + zero(bucket counters) + init out=fcb ----------------
__global__ __launch_bounds__(256) void k_prep(const float* __restrict__ W1,
                                              unsigned short* __restrict__ b1hi, unsigned short* __restrict__ b1lo,
                                              const float* __restrict__ W2,
                                              unsigned short* __restrict__ b2hi, unsigned short* __restrict__ b2lo,
                                              int* __restrict__ csr, int* __restrict__ ovfCnt,
                                              float* __restrict__ out, const float* __restrict__ fcb,
                                              int N, int B) {
    int b = blockIdx.x;
    if (b < 8)  { packW_body<256>(W1, b1hi, b1lo, b, threadIdx.x); return; }       // 4*8*64 = 8 blocks exact
    if (b < 10) { packW_body<64>(W2, b2hi, b2lo, b - 8, threadIdx.x); return; }    // 4*2*64 = 2 blocks exact
    int i = (b - 10) * 256 + threadIdx.x;
    if (i < N) csr[(size_t)i * CSR_STRIDE] = 0;
    if (i < B) out[i] = fcb[0];
    if (i == 0) *ovfCnt = 0;
}

// ---------------- r22: single-pass CSR build, counter in bucket line ----------------
// Bound by scattered LLC ops (r19: MLP null); r22 line-merge (atomic + store on
// the SAME 64B line for ~92% of edges) took it below the 60µs fill threshold.
// r17 lesson: do NOT grid-fuse this kernel with MFMA work.
__global__ void k_build(const int* __restrict__ src, const int* __restrict__ dst,
                        int* __restrict__ csr,
                        int* __restrict__ ovfCnt, int2* __restrict__ ovf, int E) {
    int i = (blockIdx.x * blockDim.x + threadIdx.x) * 4;
    if (i + 3 < E) {
        int4 d4 = *(const int4*)(dst + i);
        int4 s4 = *(const int4*)(src + i);
        int p0 = atomicAdd(&csr[(size_t)d4.x * CSR_STRIDE], 1);
        int p1 = atomicAdd(&csr[(size_t)d4.y * CSR_STRIDE], 1);
        int p2 = atomicAdd(&csr[(size_t)d4.z * CSR_STRIDE], 1);
        int p3 = atomicAdd(&csr[(size_t)d4.w * CSR_STRIDE], 1);
        if (p0 < CSR_STRIDE - 1) csr[(size_t)d4.x * CSR_STRIDE + 1 + p0] = s4.x;
        else { int o = atomicAdd(ovfCnt, 1); ovf[o] = make_int2(d4.x, s4.x); }
        if (p1 < CSR_STRIDE - 1) csr[(size_t)d4.y * CSR_STRIDE + 1 + p1] = s4.y;
        else { int o = atomicAdd(ovfCnt, 1); ovf[o] = make_int2(d4.y, s4.y); }
        if (p2 < CSR_STRIDE - 1) csr[(size_t)d4.z * CSR_STRIDE + 1 + p2] = s4.z;
        else { int o = atomicAdd(ovfCnt, 1); ovf[o] = make_int2(d4.z, s4.z); }
        if (p3 < CSR_STRIDE - 1) csr[(size_t)d4.w * CSR_STRIDE + 1 + p3] = s4.w;
        else { int o = atomicAdd(ovfCnt, 1); ovf[o] = make_int2(d4.w, s4.w); }
    } else {
        for (int j = i; j < E; j++) {
            int d = dst[j], s = src[j];
            int p = atomicAdd(&csr[(size_t)d * CSR_STRIDE], 1);
            if (p < CSR_STRIDE - 1) csr[(size_t)d * CSR_STRIDE + 1 + p] = s;
            else { int o = atomicAdd(ovfCnt, 1); ovf[o] = make_int2(d, s); }
        }
    }
}

// ---------------- MFMA GEMM body: XW(fp16) = X[N,K] @ W[K,64] + fused logits ----------------
// Split-precision bf16 (r10): 3 MFMAs (AhBh+AlBh+AhBl) => ~16-bit mantissa.
// r23: HAND SOFTWARE PIPELINE. r22 PMC showed 61µs, MfmaUtil 5.9%, VALUBusy
// 13.6%, HBM 13%, VGPR=28 — pure latency exposure: the unroll(disable) loop
// serialized {X-load(HBM) + W-load(L2) -> wait -> compute} x NKC with only
// ~6 waves/SIMD (grid-limited) to overlap. Fix: X 2-deep + W 1-deep prefetch
// with NAMED registers (rule #20: runtime-indexed reg arrays -> scratch;
// r4/r6 history: full unroll spilled). Clamped indices keep pipeline in-bounds.
// ~130 VGPR, no spill; occupancy unchanged (grid-limited).
template <int K>
__device__ __forceinline__ void mfma_body(const float* __restrict__ X,
                                          const unsigned short* __restrict__ Bhi,
                                          const unsigned short* __restrict__ Blo,
                                          const float* __restrict__ a_s, const float* __restrict__ a_d,
                                          __half* __restrict__ XW, float* __restrict__ Ssrc,
                                          float* __restrict__ Sdst, int N, int blk) {
    constexpr int NKC = K / 32;
    int t = threadIdx.x, lane = t & 63, wid = t >> 6;
    int mtile = blk * 4 + wid;
    if (mtile * 16 >= N) return;
    int m0 = mtile * 16;
    int qd = lane >> 4, col = lane & 15;

    int rA = m0 + col;
    rA = rA < N ? rA : N - 1;
    const float* xrow = X + (size_t)rA * K + qd * 8;

    const short8* bh = (const short8*)Bhi;
    const short8* bl = (const short8*)Blo;

    f32x4 acc[4];
    #pragma unroll
    for (int ct = 0; ct < 4; ct++) acc[ct] = (f32x4){0.f, 0.f, 0.f, 0.f};

    auto xp = [&](int kc) { int k2 = kc < NKC ? kc : NKC - 1; return xrow + k2 * 32; };
    auto wi = [&](int ct, int kc) { int k2 = kc < NKC ? kc : NKC - 1; return (ct * NKC + k2) * 64 + lane; };

    // pipeline prologue: X for kc=0,1; W for kc=0
    float4 xa0 = *(const float4*)xp(0), xb0 = *(const float4*)(xp(0) + 4);
    float4 xa1 = *(const float4*)xp(1), xb1 = *(const float4*)(xp(1) + 4);
    short8 wh0 = bh[wi(0, 0)], wl0 = bl[wi(0, 0)];
    short8 wh1 = bh[wi(1, 0)], wl1 = bl[wi(1, 0)];
    short8 wh2 = bh[wi(2, 0)], wl2 = bl[wi(2, 0)];
    short8 wh3 = bh[wi(3, 0)], wl3 = bl[wi(3, 0)];

    #pragma clang loop unroll(disable)
    for (int kc = 0; kc < NKC; kc++) {
        // issue kc+2 X loads (HBM latency hidden under 2 iterations)
        float4 nxa = *(const float4*)xp(kc + 2);
        float4 nxb = *(const float4*)(xp(kc + 2) + 4);
        // issue kc+1 W loads (L2 latency hidden under 1 iteration)
        short8 nwh0 = bh[wi(0, kc + 1)], nwl0 = bl[wi(0, kc + 1)];
        short8 nwh1 = bh[wi(1, kc + 1)], nwl1 = bl[wi(1, kc + 1)];
        short8 nwh2 = bh[wi(2, kc + 1)], nwl2 = bl[wi(2, kc + 1)];
        short8 nwh3 = bh[wi(3, kc + 1)], nwl3 = bl[wi(3, kc + 1)];

        // convert current x (arrived 2 iterations ago)
        float xv[8] = {xa0.x, xa0.y, xa0.z, xa0.w, xb0.x, xb0.y, xb0.z, xb0.w};
        short8 ah, al;
        #pragma unroll
        for (int j = 0; j < 8; j++) {
            unsigned short h = f2bf(xv[j]);
            ah[j] = (short)h;
            al[j] = (short)f2bf(xv[j] - bf2f(h));
        }

        // MFMAs with current W (arrived 1 iteration ago)
        acc[0] = __builtin_amdgcn_mfma_f32_16x16x32_bf16(ah, wh0, acc[0], 0, 0, 0);
        acc[0] = __builtin_amdgcn_mfma_f32_16x16x32_bf16(al, wh0, acc[0], 0, 0, 0);
        acc[0] = __builtin_amdgcn_mfma_f32_16x16x32_bf16(ah, wl0, acc[0], 0, 0, 0);
        acc[1] = __builtin_amdgcn_mfma_f32_16x16x32_bf16(ah, wh1, acc[1], 0, 0, 0);
        acc[1] = __builtin_amdgcn_mfma_f32_16x16x32_bf16(al, wh1, acc[1], 0, 0, 0);
        acc[1] = __builtin_amdgcn_mfma_f32_16x16x32_bf16(ah, wl1, acc[1], 0, 0, 0);
        acc[2] = __builtin_amdgcn_mfma_f32_16x16x32_bf16(ah, wh2, acc[2], 0, 0, 0);
        acc[2] = __builtin_amdgcn_mfma_f32_16x16x32_bf16(al, wh2, acc[2], 0, 0, 0);
        acc[2] = __builtin_amdgcn_mfma_f32_16x16x32_bf16(ah, wl2, acc[2], 0, 0, 0);
        acc[3] = __builtin_amdgcn_mfma_f32_16x16x32_bf16(ah, wh3, acc[3], 0, 0, 0);
        acc[3] = __builtin_amdgcn_mfma_f32_16x16x32_bf16(al, wh3, acc[3], 0, 0, 0);
        acc[3] = __builtin_amdgcn_mfma_f32_16x16x32_bf16(ah, wl3, acc[3], 0, 0, 0);

        // rotate pipeline registers
        xa0 = xa1; xb0 = xb1; xa1 = nxa; xb1 = nxb;
        wh0 = nwh0; wl0 = nwl0; wh1 = nwh1; wl1 = nwl1;
        wh2 = nwh2; wl2 = nwl2; wh3 = nwh3; wl3 = nwl3;
    }

    float asx[4], adx[4];
    #pragma unroll
    for (int ct = 0; ct < 4; ct++) {
        asx[ct] = a_s[ct * 16 + col];
        adx[ct] = a_d[ct * 16 + col];
    }
    #pragma unroll
    for (int r = 0; r < 4; r++) {
        int row = m0 + qd * 4 + r;
        if (row < N) {
            float vs = 0.f, vd = 0.f;
            #pragma unroll
            for (int ct = 0; ct < 4; ct++) {
                float v = acc[ct][r];
                XW[(size_t)row * 64 + ct * 16 + col] = __float2half(v);
                vs += v * asx[ct];
                vd += v * adx[ct];
            }
            #pragma unroll
            for (int d = 1; d < 16; d <<= 1) {
                vs += __shfl_xor(vs, d);
                vd += __shfl_xor(vd, d);
            }
            if (col == 0) { Ssrc[row] = vs; Sdst[row] = vd; }
        }
    }
}

template <int K>
__global__ __launch_bounds__(256) void k_mfma(const float* __restrict__ X,
                                              const unsigned short* __restrict__ Bhi,
                                              const unsigned short* __restrict__ Blo,
                                              const float* __restrict__ a_s, const float* __restrict__ a_d,
                                              __half* __restrict__ XW, float* __restrict__ Ssrc,
                                              float* __restrict__ Sdst, int N) {
    mfma_body<K>(X, Bhi, Blo, a_s, a_d, XW, Ssrc, Sdst, N, blockIdx.x);
}

// ---------------- attention + aggregate: FOUR nodes per wave (r16) ----------------
// 16 lanes per node (q=node slot, c=feature quad); all 16 lanes carry the output
// row. NO-MAX softmax (r16: ratio identical up to ~1e-7, tol 2^-9). Denom off
// critical path; 4-shfl reduce in epilogue. First batch + self loads hoisted.
// r22: deg comes FREE from csr bucket slot 0 (same 64B line as edge slots 1-15).
// r21: direct-index mode — uiL!=nullptr => slot i processes node
// (i<Bn ? uiL[i] : miL[i-Bn]). r22: in that mode the HEAD IS FUSED — no h2
// store; dot(h2, fcW half) reduced across the 16-lane group and atomicAdd'ed
// into out[i] (init=fcb in prep). Each out[i] gets exactly 2 adds (u + m).
__global__ __launch_bounds__(256) void k_attn(const __half* __restrict__ XW, const float* __restrict__ Ssrc,
                                              const float* __restrict__ Sdst, const int* __restrict__ csr,
                                              const int* __restrict__ ovfCnt, const int2* __restrict__ ovf,
                                              const int* __restrict__ uiL, const int* __restrict__ miL, int Bn,
                                              const float* __restrict__ bias, float* __restrict__ H,
                                              const float* __restrict__ fcW, float* __restrict__ out,
                                              int N, int do_relu) {
    int t = threadIdx.x, lane = t & 63, wid = t >> 6;
    int q = lane >> 4;                        // node slot within wave
    int c = lane & 15;                        // feature quad
    int i4 = (blockIdx.x * 4 + wid) * 4 + q;  // 16 work-items per block
    bool valid;
    int n;
    if (uiL) {
        valid = i4 < 2 * Bn;
        n = valid ? (i4 < Bn ? uiL[i4] : miL[i4 - Bn]) : 0;
    } else {
        valid = i4 < N;
        n = valid ? i4 : 0;
    }
    int nc = n;                               // safe node (0) when invalid; never stored

    int st = nc * CSR_STRIDE;
    int d = csr[st];                          // counter in slot 0 (line-shared with slots 1-15)
    float sd = Sdst[nc];
    int d31 = d < CSR_STRIDE - 1 ? d : CSR_STRIDE - 1;
    int dcap = d < 16 ? d : 16;

    // edge slot: lane (q,c) holds edge c of node q (pad lanes -> row 0, weight 0)
    int myS = 0;
    if (c < dcap) myS = csr[st + 1 + c];

    // first-batch row indices (depend only on csr) -> issue loads before softmax
    int s0 = __shfl(myS, q * 16 + 0), s1 = __shfl(myS, q * 16 + 1);
    int s2 = __shfl(myS, q * 16 + 2), s3 = __shfl(myS, q * 16 + 3);
    float2 rs = *(const float2*)(XW + (size_t)nc * 64 + c * 4);
    float2 r0 = *(const float2*)(XW + (size_t)s0 * 64 + c * 4);
    float2 r1 = *(const float2*)(XW + (size_t)s1 * 64 + c * 4);
    float2 r2 = *(const float2*)(XW + (size_t)s2 * 64 + c * 4);
    float2 r3 = *(const float2*)(XW + (size_t)s3 * 64 + c * 4);

    // logits -> weights (no max subtraction)
    float wself = __expf(lrelu(Ssrc[nc] + sd));
    float myW = 0.f;
    if (c < dcap) myW = __expf(lrelu(Ssrc[myS] + sd));
    float dpart = myW + ((c == 0) ? wself : 0.f);

    float4 acc4 = make_float4(0.f, 0.f, 0.f, 0.f);
    auto accum = [&](float2 raw, float w) {
        const __half2* hp = (const __half2*)&raw;
        float2 f0 = __half22float2(hp[0]);
        float2 f1 = __half22float2(hp[1]);
        acc4.x += w * f0.x; acc4.y += w * f0.y; acc4.z += w * f1.x; acc4.w += w * f1.y;
    };

    float w0 = __shfl(myW, q * 16 + 0), w1 = __shfl(myW, q * 16 + 1);
    float w2 = __shfl(myW, q * 16 + 2), w3 = __shfl(myW, q * 16 + 3);
    accum(rs, wself);
    accum(r0, w0); accum(r1, w1); accum(r2, w2); accum(r3, w3);

    // remaining batches (deg > 4): 4 independent loads per round
    for (int i = 4; i < dcap; i += 4) {
        int t0 = __shfl(myS, q * 16 + i + 0), t1 = __shfl(myS, q * 16 + i + 1);
        int t2 = __shfl(myS, q * 16 + i + 2), t3 = __shfl(myS, q * 16 + i + 3);
        float2 q0 = *(const float2*)(XW + (size_t)t0 * 64 + c * 4);
        float2 q1 = *(const float2*)(XW + (size_t)t1 * 64 + c * 4);
        float2 q2 = *(const float2*)(XW + (size_t)t2 * 64 + c * 4);
        float2 q3 = *(const float2*)(XW + (size_t)t3 * 64 + c * 4);
        float v0 = __shfl(myW, q * 16 + i + 0), v1 = __shfl(myW, q * 16 + i + 1);
        float v2 = __shfl(myW, q * 16 + i + 2), v3 = __shfl(myW, q * 16 + i + 3);
        accum(q0, v0); accum(q1, v1); accum(q2, v2); accum(q3, v3);
    }

    // tail (16 < deg <= 31): per-16-lane-group serial
    for (int i = 16; i < d31; i++) {
        int s = csr[st + 1 + i];
        float w = __expf(lrelu(Ssrc[s] + sd));
        if (c == 0) dpart += w;
        float2 qv = *(const float2*)(XW + (size_t)s * 64 + c * 4);
        accum(qv, w);
    }

    // overflow edges (deg > 31): expected count 0; one uniform load + branch
    int nov = *ovfCnt;
    if (nov > 0) {
        for (int j = 0; j < nov; j++) {
            int2 e = ovf[j];
            if (e.x == nc) {
                float w = __expf(lrelu(Ssrc[e.y] + sd));
                if (c == 0) dpart += w;
                float2 qv = *(const float2*)(XW + (size_t)e.y * 64 + c * 4);
                accum(qv, w);
            }
        }
    }

    // denom reduce within the 16-lane node group
    #pragma unroll
    for (int dd = 8; dd > 0; dd >>= 1) dpart += __shfl_xor(dpart, dd);

    if (valid) {
        float4 b4 = *(const float4*)&bias[c * 4];
        float inv = 1.f / dpart;
        float4 o;
        o.x = acc4.x * inv + b4.x;
        o.y = acc4.y * inv + b4.y;
        o.z = acc4.z * inv + b4.z;
        o.w = acc4.w * inv + b4.w;
        if (do_relu) {
            o.x = fmaxf(o.x, 0.f); o.y = fmaxf(o.y, 0.f);
            o.z = fmaxf(o.z, 0.f); o.w = fmaxf(o.w, 0.f);
        }
        if (!uiL) {
            *(float4*)&H[(size_t)n * 64 + c * 4] = o;
        } else {
            // fused head: dot(h2_row, fcW half) -> out[i]
            const float* fw = fcW + (i4 < Bn ? 0 : 64) + c * 4;
            float dot = o.x * fw[0] + o.y * fw[1] + o.z * fw[2] + o.w * fw[3];
            #pragma unroll
            for (int dd = 8; dd > 0; dd >>= 1) dot += __shfl_xor(dot, dd);
            if (c == 0) atomicAdd(&out[i4 < Bn ? i4 : i4 - Bn], dot);
        }
    }
}

extern "C" void kernel_launch(void* const* d_in, const int* in_sizes, int n_in,
                              void* d_out, int out_size, void* d_ws, size_t ws_size,
                              hipStream_t stream) {
    const float* x   = (const float*)d_in[0];
    const int*   ei  = (const int*)d_in[1];
    const int*   ui  = (const int*)d_in[2];
    const int*   mi  = (const int*)d_in[3];
    const float* W1  = (const float*)d_in[4];
    const float* as1 = (const float*)d_in[5];
    const float* ad1 = (const float*)d_in[6];
    const float* b1  = (const float*)d_in[7];
    const float* W2  = (const float*)d_in[8];
    const float* as2 = (const float*)d_in[9];
    const float* ad2 = (const float*)d_in[10];
    const float* b2  = (const float*)d_in[11];
    const float* fcW = (const float*)d_in[12];
    const float* fcb = (const float*)d_in[13];
    float* out = (float*)d_out;

    const int Hdim = in_sizes[5];            // 64
    const int FIN  = in_sizes[4] / Hdim;     // 256
    const int N    = in_sizes[0] / FIN;      // 100000
    const int E    = in_sizes[1] / 2;        // 1000000
    const int B    = in_sizes[2];            // 16384

    char* w = (char*)d_ws;
    auto alloc = [&](size_t bytes) -> void* {
        void* p = (void*)w;
        w += (bytes + 255) & ~(size_t)255;
        return p;
    };
    __half* xw  = (__half*)alloc((size_t)N * 64 * 2);
    float* hbuf = (float*)alloc((size_t)N * 64 * 4);
    float* ssrc = (float*)alloc((size_t)N * 4);
    float* sdst = (float*)alloc((size_t)N * 4);
    int* csr    = (int*)alloc((size_t)N * CSR_STRIDE * 4);
    int* ovfCnt = (int*)alloc(256);
    int2* ovf   = (int2*)alloc((size_t)65536 * 8);
    unsigned short* b1hi = (unsigned short*)alloc((size_t)4 * 8 * 64 * 8 * 2);
    unsigned short* b1lo = (unsigned short*)alloc((size_t)4 * 8 * 64 * 8 * 2);
    unsigned short* b2hi = (unsigned short*)alloc((size_t)4 * 2 * 64 * 8 * 2);
    unsigned short* b2lo = (unsigned short*)alloc((size_t)4 * 2 * 64 * 8 * 2);

    const int* esrc = ei;
    const int* edst = ei + E;

    const int mfmaBlocks = ((N + 15) / 16 + 3) / 4;   // 1563
    const int attnBlocks = (N + 15) / 16;             // 6250
    const int attn2Blocks = (2 * B + 15) / 16;        // 2048

    // --- prep: packW1 + packW2 + zero(bucket counters) + out=fcb ---
    int prepBlocks = 10 + (N + 255) / 256;
    k_prep<<<prepBlocks, 256, 0, stream>>>(W1, b1hi, b1lo, W2, b2hi, b2lo, csr, ovfCnt, out, fcb, N, B);

    // --- single-pass CSR build (counter-in-bucket-line) ---
    k_build<<<(E / 4 + 255) / 256, 256, 0, stream>>>(esrc, edst, csr, ovfCnt, ovf, E);

    // --- layer 1 (full graph) ---
    k_mfma<256><<<mfmaBlocks, 256, 0, stream>>>(x, b1hi, b1lo, as1, ad1, xw, ssrc, sdst, N);
    k_attn<<<attnBlocks, 256, 0, stream>>>(xw, ssrc, sdst, csr, ovfCnt, ovf,
                                           (const int*)nullptr, (const int*)nullptr, 0,
                                           b1, hbuf, (const float*)nullptr, (float*)nullptr, N, 1);

    // --- layer 2 (mfma full; attn driven by ui/mi with fused head) ---
    k_mfma<64><<<mfmaBlocks, 256, 0, stream>>>(hbuf, b2hi, b2lo, as2, ad2, xw, ssrc, sdst, N);
    k_attn<<<attn2Blocks, 256, 0, stream>>>(xw, ssrc, sdst, csr, ovfCnt, ovf,
                                            ui, mi, B, b2, hbuf, fcW, out, N, 0);
}

// Round 13
// 301.524 us; speedup vs baseline: 1.0152x; 1.0152x over previous
//
#include <hip/hip_runtime.h>
#include <hip/hip_bf16.h>
#include <hip/hip_fp16.h>

#define LRELU_SLOPE 0.2f
#define CSR_STRIDE 32   // bucket = 32 ints: slot 0 = count, slots 1..31 = sources

__device__ __forceinline__ float lrelu(float x) { return x > 0.f ? x : LRELU_SLOPE * x; }

typedef __attribute__((ext_vector_type(8))) short short8;
typedef __attribute__((ext_vector_type(4))) float f32x4;

__device__ __forceinline__ unsigned short f2bf(float f) {
    unsigned u = __builtin_bit_cast(unsigned, f);
    u = (u + 0x7FFFu + ((u >> 16) & 1u)) >> 16;  // RNE
    return (unsigned short)u;
}
__device__ __forceinline__ float bf2f(unsigned short b) {
    unsigned u = ((unsigned)b) << 16;
    return __builtin_bit_cast(float, u);
}

// ---------------- W pre-pack body: fp32 [K][64] -> B-fragment bf16 hi/lo ----------------
template <int K>
__device__ __forceinline__ void packW_body(const float* __restrict__ W,
                                           unsigned short* __restrict__ Bhi,
                                           unsigned short* __restrict__ Blo,
                                           int blk, int t) {
    constexpr int NKC = K / 32;
    int g = blk * 256 + t;
    if (g >= 4 * NKC * 64) return;
    int lane = g & 63;
    int kc = (g >> 6) % NKC;
    int ct = g / (64 * NKC);
    int qd = lane >> 4, col = lane & 15;
    #pragma unroll
    for (int j = 0; j < 8; j++) {
        int k = kc * 32 + qd * 8 + j;
        float w = W[(size_t)k * 64 + ct * 16 + col];
        unsigned short h = f2bf(w);
        float rem = w - bf2f(h);
        Bhi[(size_t)g * 8 + j] = h;
        Blo[(size_t)g * 8 + j] = f2bf(rem);
    }
}

// ---------------- prep — packW1 + packW2 + zero(bucket counters) + init out=fcb ----------------
__global__ __launch_bounds__(256) void k_prep(const float* __restrict__ W1,
                                              unsigned short* __restrict__ b1hi, unsigned short* __restrict__ b1lo,
                                              const float* __restrict__ W2,
                                              unsigned short* __restrict__ b2hi, unsigned short* __restrict__ b2lo,
                                              int* __restrict__ csr, int* __restrict__ ovfCnt,
                                              float* __restrict__ out, const float* __restrict__ fcb,
                                              int N, int B) {
    int b = blockIdx.x;
    if (b < 8)  { packW_body<256>(W1, b1hi, b1lo, b, threadIdx.x); return; }       // 4*8*64 = 8 blocks exact
    if (b < 10) { packW_body<64>(W2, b2hi, b2lo, b - 8, threadIdx.x); return; }    // 4*2*64 = 2 blocks exact
    int i = (b - 10) * 256 + threadIdx.x;
    if (i < N) csr[(size_t)i * CSR_STRIDE] = 0;
    if (i < B) out[i] = fcb[0];
    if (i == 0) *ovfCnt = 0;
}

// ---------------- r22: single-pass CSR build, counter in bucket line ----------------
// Bound by scattered LLC ops (r19: MLP null); r22 line-merge (atomic + store on
// the SAME 64B line for ~92% of edges) took it below the 60µs fill threshold.
// r17 lesson: do NOT grid-fuse this kernel with MFMA work.
__global__ void k_build(const int* __restrict__ src, const int* __restrict__ dst,
                        int* __restrict__ csr,
                        int* __restrict__ ovfCnt, int2* __restrict__ ovf, int E) {
    int i = (blockIdx.x * blockDim.x + threadIdx.x) * 4;
    if (i + 3 < E) {
        int4 d4 = *(const int4*)(dst + i);
        int4 s4 = *(const int4*)(src + i);
        int p0 = atomicAdd(&csr[(size_t)d4.x * CSR_STRIDE], 1);
        int p1 = atomicAdd(&csr[(size_t)d4.y * CSR_STRIDE], 1);
        int p2 = atomicAdd(&csr[(size_t)d4.z * CSR_STRIDE], 1);
        int p3 = atomicAdd(&csr[(size_t)d4.w * CSR_STRIDE], 1);
        if (p0 < CSR_STRIDE - 1) csr[(size_t)d4.x * CSR_STRIDE + 1 + p0] = s4.x;
        else { int o = atomicAdd(ovfCnt, 1); ovf[o] = make_int2(d4.x, s4.x); }
        if (p1 < CSR_STRIDE - 1) csr[(size_t)d4.y * CSR_STRIDE + 1 + p1] = s4.y;
        else { int o = atomicAdd(ovfCnt, 1); ovf[o] = make_int2(d4.y, s4.y); }
        if (p2 < CSR_STRIDE - 1) csr[(size_t)d4.z * CSR_STRIDE + 1 + p2] = s4.z;
        else { int o = atomicAdd(ovfCnt, 1); ovf[o] = make_int2(d4.z, s4.z); }
        if (p3 < CSR_STRIDE - 1) csr[(size_t)d4.w * CSR_STRIDE + 1 + p3] = s4.w;
        else { int o = atomicAdd(ovfCnt, 1); ovf[o] = make_int2(d4.w, s4.w); }
    } else {
        for (int j = i; j < E; j++) {
            int d = dst[j], s = src[j];
            int p = atomicAdd(&csr[(size_t)d * CSR_STRIDE], 1);
            if (p < CSR_STRIDE - 1) csr[(size_t)d * CSR_STRIDE + 1 + p] = s;
            else { int o = atomicAdd(ovfCnt, 1); ovf[o] = make_int2(d, s); }
        }
    }
}

// ---------------- MFMA GEMM: XW(fp16) = X[N,K] @ W[K,64] + fused logits ----------------
// Split-precision bf16 (r10): 3 MFMAs (AhBh+AlBh+AhBl) => ~16-bit mantissa.
// r24: K-SPLIT ACROSS WAVE PAIRS. r22 PMC: latency-bound (MfmaUtil 6%, VALU 13%,
// HBM 13%) at ~6 waves/SIMD (grid-limited). r23's named-register pipeline was
// DEFEATED by the compiler (VGPR 44 not ~130 — loads sunk back to uses; 306µs).
// TLP fix the compiler can't undo: each wave computes HALF of K (NKH=NKC/2 kc
// chunks); wave pairs combine partial accs via 8KB LDS (red[pair][ct][lane],
// 16B/lane contiguous = conflict-free); even wave runs the epilogue. 2x waves
// (12504), half the per-wave latency chain. Same X/W traffic. Inner loop back
// to r22's simple 28-VGPR form. No returns before the barrier (mtile clamped,
// row<N guards stores). acc reassociation: (kc0-3)+(kc4-7) vs sequential —
// 1-2 ulp, absmax unchanged at tol 2^-9.
template <int K>
__global__ __launch_bounds__(256) void k_mfma(const float* __restrict__ X,
                                              const unsigned short* __restrict__ Bhi,
                                              const unsigned short* __restrict__ Blo,
                                              const float* __restrict__ a_s, const float* __restrict__ a_d,
                                              __half* __restrict__ XW, float* __restrict__ Ssrc,
                                              float* __restrict__ Sdst, int N) {
    constexpr int NKC = K / 32;
    constexpr int NKH = NKC / 2;              // kc chunks per wave (256->4, 64->1)
    __shared__ f32x4 red[2][4][64];           // [pair][ct][lane] partial accs (8KB)

    int t = threadIdx.x, lane = t & 63, wid = t >> 6;
    int pair = wid >> 1, half = wid & 1;
    int mtile = blockIdx.x * 2 + pair;
    int maxt = (N + 15) / 16 - 1;
    int mt = mtile < maxt ? mtile : maxt;     // clamp (duplicate compute, identical stores)
    int m0 = mt * 16;
    int qd = lane >> 4, col = lane & 15;

    int rA = m0 + col;
    rA = rA < N ? rA : N - 1;
    const float* xrow = X + (size_t)rA * K + half * (NKH * 32) + qd * 8;

    const short8* bh = (const short8*)Bhi;
    const short8* bl = (const short8*)Blo;

    f32x4 acc[4];
    #pragma unroll
    for (int ct = 0; ct < 4; ct++) acc[ct] = (f32x4){0.f, 0.f, 0.f, 0.f};

    #pragma clang loop unroll(disable)
    for (int kc = 0; kc < NKH; kc++) {
        const float* xp = xrow + kc * 32;
        float4 xa = *(const float4*)xp;
        float4 xb = *(const float4*)(xp + 4);
        float xv[8] = {xa.x, xa.y, xa.z, xa.w, xb.x, xb.y, xb.z, xb.w};
        short8 ah, al;
        #pragma unroll
        for (int j = 0; j < 8; j++) {
            unsigned short h = f2bf(xv[j]);
            ah[j] = (short)h;
            al[j] = (short)f2bf(xv[j] - bf2f(h));
        }
        int kcg = half * NKH + kc;
        #pragma unroll
        for (int ct = 0; ct < 4; ct++) {
            short8 wh = bh[(ct * NKC + kcg) * 64 + lane];
            short8 wl = bl[(ct * NKC + kcg) * 64 + lane];
            acc[ct] = __builtin_amdgcn_mfma_f32_16x16x32_bf16(ah, wh, acc[ct], 0, 0, 0);
            acc[ct] = __builtin_amdgcn_mfma_f32_16x16x32_bf16(al, wh, acc[ct], 0, 0, 0);
            acc[ct] = __builtin_amdgcn_mfma_f32_16x16x32_bf16(ah, wl, acc[ct], 0, 0, 0);
        }
    }

    // combine K-halves: odd wave publishes, even wave reduces + epilogue
    if (half == 1) {
        #pragma unroll
        for (int ct = 0; ct < 4; ct++) red[pair][ct][lane] = acc[ct];
    }
    __syncthreads();
    if (half == 1) return;

    #pragma unroll
    for (int ct = 0; ct < 4; ct++) acc[ct] += red[pair][ct][lane];

    float asx[4], adx[4];
    #pragma unroll
    for (int ct = 0; ct < 4; ct++) {
        asx[ct] = a_s[ct * 16 + col];
        adx[ct] = a_d[ct * 16 + col];
    }
    #pragma unroll
    for (int r = 0; r < 4; r++) {
        int row = m0 + qd * 4 + r;
        if (row < N) {
            float vs = 0.f, vd = 0.f;
            #pragma unroll
            for (int ct = 0; ct < 4; ct++) {
                float v = acc[ct][r];
                XW[(size_t)row * 64 + ct * 16 + col] = __float2half(v);
                vs += v * asx[ct];
                vd += v * adx[ct];
            }
            #pragma unroll
            for (int d = 1; d < 16; d <<= 1) {
                vs += __shfl_xor(vs, d);
                vd += __shfl_xor(vd, d);
            }
            if (col == 0) { Ssrc[row] = vs; Sdst[row] = vd; }
        }
    }
}

// ---------------- attention + aggregate: FOUR nodes per wave (r16) ----------------
// 16 lanes per node (q=node slot, c=feature quad); all 16 lanes carry the output
// row. NO-MAX softmax (r16: ratio identical up to ~1e-7, tol 2^-9). Denom off
// critical path; 4-shfl reduce in epilogue. First batch + self loads hoisted.
// r22: deg comes FREE from csr bucket slot 0 (same 64B line as edge slots 1-15).
// r21: direct-index mode — uiL!=nullptr => slot i processes node
// (i<Bn ? uiL[i] : miL[i-Bn]). r22: in that mode the HEAD IS FUSED — no h2
// store; dot(h2, fcW half) reduced across the 16-lane group and atomicAdd'ed
// into out[i] (init=fcb in prep). Each out[i] gets exactly 2 adds (u + m).
__global__ __launch_bounds__(256) void k_attn(const __half* __restrict__ XW, const float* __restrict__ Ssrc,
                                              const float* __restrict__ Sdst, const int* __restrict__ csr,
                                              const int* __restrict__ ovfCnt, const int2* __restrict__ ovf,
                                              const int* __restrict__ uiL, const int* __restrict__ miL, int Bn,
                                              const float* __restrict__ bias, float* __restrict__ H,
                                              const float* __restrict__ fcW, float* __restrict__ out,
                                              int N, int do_relu) {
    int t = threadIdx.x, lane = t & 63, wid = t >> 6;
    int q = lane >> 4;                        // node slot within wave
    int c = lane & 15;                        // feature quad
    int i4 = (blockIdx.x * 4 + wid) * 4 + q;  // 16 work-items per block
    bool valid;
    int n;
    if (uiL) {
        valid = i4 < 2 * Bn;
        n = valid ? (i4 < Bn ? uiL[i4] : miL[i4 - Bn]) : 0;
    } else {
        valid = i4 < N;
        n = valid ? i4 : 0;
    }
    int nc = n;                               // safe node (0) when invalid; never stored

    int st = nc * CSR_STRIDE;
    int d = csr[st];                          // counter in slot 0 (line-shared with slots 1-15)
    float sd = Sdst[nc];
    int d31 = d < CSR_STRIDE - 1 ? d : CSR_STRIDE - 1;
    int dcap = d < 16 ? d : 16;

    // edge slot: lane (q,c) holds edge c of node q (pad lanes -> row 0, weight 0)
    int myS = 0;
    if (c < dcap) myS = csr[st + 1 + c];

    // first-batch row indices (depend only on csr) -> issue loads before softmax
    int s0 = __shfl(myS, q * 16 + 0), s1 = __shfl(myS, q * 16 + 1);
    int s2 = __shfl(myS, q * 16 + 2), s3 = __shfl(myS, q * 16 + 3);
    float2 rs = *(const float2*)(XW + (size_t)nc * 64 + c * 4);
    float2 r0 = *(const float2*)(XW + (size_t)s0 * 64 + c * 4);
    float2 r1 = *(const float2*)(XW + (size_t)s1 * 64 + c * 4);
    float2 r2 = *(const float2*)(XW + (size_t)s2 * 64 + c * 4);
    float2 r3 = *(const float2*)(XW + (size_t)s3 * 64 + c * 4);

    // logits -> weights (no max subtraction)
    float wself = __expf(lrelu(Ssrc[nc] + sd));
    float myW = 0.f;
    if (c < dcap) myW = __expf(lrelu(Ssrc[myS] + sd));
    float dpart = myW + ((c == 0) ? wself : 0.f);

    float4 acc4 = make_float4(0.f, 0.f, 0.f, 0.f);
    auto accum = [&](float2 raw, float w) {
        const __half2* hp = (const __half2*)&raw;
        float2 f0 = __half22float2(hp[0]);
        float2 f1 = __half22float2(hp[1]);
        acc4.x += w * f0.x; acc4.y += w * f0.y; acc4.z += w * f1.x; acc4.w += w * f1.y;
    };

    float w0 = __shfl(myW, q * 16 + 0), w1 = __shfl(myW, q * 16 + 1);
    float w2 = __shfl(myW, q * 16 + 2), w3 = __shfl(myW, q * 16 + 3);
    accum(rs, wself);
    accum(r0, w0); accum(r1, w1); accum(r2, w2); accum(r3, w3);

    // remaining batches (deg > 4): 4 independent loads per round
    for (int i = 4; i < dcap; i += 4) {
        int t0 = __shfl(myS, q * 16 + i + 0), t1 = __shfl(myS, q * 16 + i + 1);
        int t2 = __shfl(myS, q * 16 + i + 2), t3 = __shfl(myS, q * 16 + i + 3);
        float2 q0 = *(const float2*)(XW + (size_t)t0 * 64 + c * 4);
        float2 q1 = *(const float2*)(XW + (size_t)t1 * 64 + c * 4);
        float2 q2 = *(const float2*)(XW + (size_t)t2 * 64 + c * 4);
        float2 q3 = *(const float2*)(XW + (size_t)t3 * 64 + c * 4);
        float v0 = __shfl(myW, q * 16 + i + 0), v1 = __shfl(myW, q * 16 + i + 1);
        float v2 = __shfl(myW, q * 16 + i + 2), v3 = __shfl(myW, q * 16 + i + 3);
        accum(q0, v0); accum(q1, v1); accum(q2, v2); accum(q3, v3);
    }

    // tail (16 < deg <= 31): per-16-lane-group serial
    for (int i = 16; i < d31; i++) {
        int s = csr[st + 1 + i];
        float w = __expf(lrelu(Ssrc[s] + sd));
        if (c == 0) dpart += w;
        float2 qv = *(const float2*)(XW + (size_t)s * 64 + c * 4);
        accum(qv, w);
    }

    // overflow edges (deg > 31): expected count 0; one uniform load + branch
    int nov = *ovfCnt;
    if (nov > 0) {
        for (int j = 0; j < nov; j++) {
            int2 e = ovf[j];
            if (e.x == nc) {
                float w = __expf(lrelu(Ssrc[e.y] + sd));
                if (c == 0) dpart += w;
                float2 qv = *(const float2*)(XW + (size_t)e.y * 64 + c * 4);
                accum(qv, w);
            }
        }
    }

    // denom reduce within the 16-lane node group
    #pragma unroll
    for (int dd = 8; dd > 0; dd >>= 1) dpart += __shfl_xor(dpart, dd);

    if (valid) {
        float4 b4 = *(const float4*)&bias[c * 4];
        float inv = 1.f / dpart;
        float4 o;
        o.x = acc4.x * inv + b4.x;
        o.y = acc4.y * inv + b4.y;
        o.z = acc4.z * inv + b4.z;
        o.w = acc4.w * inv + b4.w;
        if (do_relu) {
            o.x = fmaxf(o.x, 0.f); o.y = fmaxf(o.y, 0.f);
            o.z = fmaxf(o.z, 0.f); o.w = fmaxf(o.w, 0.f);
        }
        if (!uiL) {
            *(float4*)&H[(size_t)n * 64 + c * 4] = o;
        } else {
            // fused head: dot(h2_row, fcW half) -> out[i]
            const float* fw = fcW + (i4 < Bn ? 0 : 64) + c * 4;
            float dot = o.x * fw[0] + o.y * fw[1] + o.z * fw[2] + o.w * fw[3];
            #pragma unroll
            for (int dd = 8; dd > 0; dd >>= 1) dot += __shfl_xor(dot, dd);
            if (c == 0) atomicAdd(&out[i4 < Bn ? i4 : i4 - Bn], dot);
        }
    }
}

extern "C" void kernel_launch(void* const* d_in, const int* in_sizes, int n_in,
                              void* d_out, int out_size, void* d_ws, size_t ws_size,
                              hipStream_t stream) {
    const float* x   = (const float*)d_in[0];
    const int*   ei  = (const int*)d_in[1];
    const int*   ui  = (const int*)d_in[2];
    const int*   mi  = (const int*)d_in[3];
    const float* W1  = (const float*)d_in[4];
    const float* as1 = (const float*)d_in[5];
    const float* ad1 = (const float*)d_in[6];
    const float* b1  = (const float*)d_in[7];
    const float* W2  = (const float*)d_in[8];
    const float* as2 = (const float*)d_in[9];
    const float* ad2 = (const float*)d_in[10];
    const float* b2  = (const float*)d_in[11];
    const float* fcW = (const float*)d_in[12];
    const float* fcb = (const float*)d_in[13];
    float* out = (float*)d_out;

    const int Hdim = in_sizes[5];            // 64
    const int FIN  = in_sizes[4] / Hdim;     // 256
    const int N    = in_sizes[0] / FIN;      // 100000
    const int E    = in_sizes[1] / 2;        // 1000000
    const int B    = in_sizes[2];            // 16384

    char* w = (char*)d_ws;
    auto alloc = [&](size_t bytes) -> void* {
        void* p = (void*)w;
        w += (bytes + 255) & ~(size_t)255;
        return p;
    };
    __half* xw  = (__half*)alloc((size_t)N * 64 * 2);
    float* hbuf = (float*)alloc((size_t)N * 64 * 4);
    float* ssrc = (float*)alloc((size_t)N * 4);
    float* sdst = (float*)alloc((size_t)N * 4);
    int* csr    = (int*)alloc((size_t)N * CSR_STRIDE * 4);
    int* ovfCnt = (int*)alloc(256);
    int2* ovf   = (int2*)alloc((size_t)65536 * 8);
    unsigned short* b1hi = (unsigned short*)alloc((size_t)4 * 8 * 64 * 8 * 2);
    unsigned short* b1lo = (unsigned short*)alloc((size_t)4 * 8 * 64 * 8 * 2);
    unsigned short* b2hi = (unsigned short*)alloc((size_t)4 * 2 * 64 * 8 * 2);
    unsigned short* b2lo = (unsigned short*)alloc((size_t)4 * 2 * 64 * 8 * 2);

    const int* esrc = ei;
    const int* edst = ei + E;

    const int mfmaBlocks = (((N + 15) / 16) + 1) / 2;  // 3125 (2 mtiles/block, K-split waves)
    const int attnBlocks = (N + 15) / 16;              // 6250
    const int attn2Blocks = (2 * B + 15) / 16;         // 2048

    // --- prep: packW1 + packW2 + zero(bucket counters) + out=fcb ---
    int prepBlocks = 10 + (N + 255) / 256;
    k_prep<<<prepBlocks, 256, 0, stream>>>(W1, b1hi, b1lo, W2, b2hi, b2lo, csr, ovfCnt, out, fcb, N, B);

    // --- single-pass CSR build (counter-in-bucket-line) ---
    k_build<<<(E / 4 + 255) / 256, 256, 0, stream>>>(esrc, edst, csr, ovfCnt, ovf, E);

    // --- layer 1 (full graph) ---
    k_mfma<256><<<mfmaBlocks, 256, 0, stream>>>(x, b1hi, b1lo, as1, ad1, xw, ssrc, sdst, N);
    k_attn<<<attnBlocks, 256, 0, stream>>>(xw, ssrc, sdst, csr, ovfCnt, ovf,
                                           (const int*)nullptr, (const int*)nullptr, 0,
                                           b1, hbuf, (const float*)nullptr, (float*)nullptr, N, 1);

    // --- layer 2 (mfma full; attn driven by ui/mi with fused head) ---
    k_mfma<64><<<mfmaBlocks, 256, 0, stream>>>(hbuf, b2hi, b2lo, as2, ad2, xw, ssrc, sdst, N);
    k_attn<<<attn2Blocks, 256, 0, stream>>>(xw, ssrc, sdst, csr, ovfCnt, ovf,
                                            ui, mi, B, b2, hbuf, fcW, out, N, 0);
}